// Round 6
// baseline (9209.894 us; speedup 1.0000x reference)
//
#include <hip/hip_runtime.h>
#include <math.h>

// Problem constants
#define NCLS 19
#define FDIM 256
#define DDIR 1024
#define NPIX 8192
#define KPAD 768            // per-class compacted-column padding (max n_c ~ 500)
#define NSWEEP 5
#define NROUND 255
#define NSTEP (NSWEEP*NROUND)
#define NPAIR 128
#define TRI_N 32896         // 256*257/2
#define NGROUP 8256         // 128*129/2
#define NSEG 32             // 8192 / 256 label segments
#define VST 66              // replay V-state row stride (64 + 2 pad)
#define FLAGSTRIDE 16       // pad step-flags to 64B lines (kill LLC line ping-pong)

// ---- device-global workspace ----
__device__ float g_sum[NCLS][FDIM];
__device__ float g_cntf[NCLS];
__device__ float g_ns[NCLS];
__device__ float g_mu[NCLS][FDIM];
__device__ int   g_rank[NPIX];
__device__ int   g_segcnt[NSEG][NCLS];
__device__ int   g_segoff[NSEG][NCLS];
__device__ float g_X[NCLS][FDIM][KPAD];
__device__ float g_cov[NCLS][FDIM][FDIM];
__device__ unsigned long long g_rotlog[NCLS][NSTEP][NPAIR];  // packed (c,s)
__device__ int   g_step[NCLS*FLAGSTRIDE];
__device__ float g_eval[NCLS][FDIM];
__device__ float g_Vt[NCLS][FDIM][FDIM];
__device__ float g_W[NCLS][FDIM][FDIM];
__device__ float g_M[NCLS][DDIR][FDIM];
__device__ float g_mom[NCLS][DDIR][4];

union PackCS { float2 f; unsigned long long u; };

// round-robin tournament pairing: 255 fixed, 0..254 rotate
__device__ __forceinline__ void get_pair(int r, int s, int& p, int& q) {
    int a, b;
    if (s == 0) { a = NROUND; b = r; }
    else {
        a = r + s; if (a >= NROUND) a -= NROUND;
        b = r - s; if (b < 0) b += NROUND;
    }
    p = min(a, b); q = max(a, b);
}

__device__ __forceinline__ int tidx(int i, int j) { return ((i*(i+1))>>1) + j; } // i>=j
__device__ __forceinline__ int tidx2(int a, int b) { return a >= b ? tidx(a,b) : tidx(b,a); }

// ---- K0: zero compacted buffer + flags + segment counters ----
__global__ __launch_bounds__(1024) void k_zero() {
    int idx = blockIdx.x*blockDim.x + threadIdx.x;
    const int total = NCLS*FDIM*KPAD;
    float* x = &g_X[0][0][0];
    for (int i = idx; i < total; i += gridDim.x*blockDim.x) x[i] = 0.f;
    if (idx < NCLS*FLAGSTRIDE) g_step[idx] = 0;
    if (idx < NSEG*NCLS) (&g_segcnt[0][0])[idx] = 0;
}

// ---- K1: per-class sums per feature + counts (block = feature f) ----
__global__ void k_sums(const float* __restrict__ feat, const int* __restrict__ lab) {
    __shared__ float acc[NCLS][256];
    __shared__ float cnt[NCLS][256];
    int t = threadIdx.x;
    int f = blockIdx.x;
    for (int c = 0; c < NCLS; ++c) { acc[c][t] = 0.f; cnt[c][t] = 0.f; }
    for (int j = 0; j < NPIX/256; ++j) {
        int n = t + 256*j;
        int b = n >> 12, hw = n & 4095;
        float v = feat[(size_t)b*1048576 + (size_t)f*4096 + hw];
        int c = lab[n];
        acc[c][t] += v;
        cnt[c][t] += 1.f;
    }
    __syncthreads();
    for (int off = 128; off > 0; off >>= 1) {
        if (t < off)
            for (int c = 0; c < NCLS; ++c) {
                acc[c][t] += acc[c][t+off];
                cnt[c][t] += cnt[c][t+off];
            }
        __syncthreads();
    }
    if (t < NCLS) {
        g_sum[t][f] = acc[t][0];
        if (f == 0) g_cntf[t] = cnt[t][0];
    }
}

// ---- K2: ns and mu ----
__global__ void k_musetup() {
    int t = threadIdx.x;
    if (t < NCLS) g_ns[t] = fmaxf(g_cntf[t], 1.f);
    __syncthreads();
    for (int c = 0; c < NCLS; ++c)
        g_mu[c][t] = g_sum[c][t] / g_ns[c];
}

// ---- K3a: deterministic per-segment rank + per-segment class counts ----
__global__ void k_rank(const int* __restrict__ lab) {
    __shared__ int sl[256];
    int seg = blockIdx.x, t = threadIdx.x;
    int n = seg*256 + t;
    int c = lab[n];
    sl[t] = c;
    __syncthreads();
    int rnk = 0, tot = 0;
    for (int i = 0; i < 256; ++i) {
        int e = sl[i];
        if (e == c) { tot += 1; if (i < t) rnk += 1; }
    }
    g_rank[n] = rnk;
    if (rnk == 0) g_segcnt[seg][c] = tot;
}

// ---- K3b: exclusive scan of segment counts per class ----
__global__ void k_segscan() {
    int c = threadIdx.x;
    if (c < NCLS) {
        int run = 0;
        for (int s = 0; s < NSEG; ++s) {
            g_segoff[s][c] = run;
            run += g_segcnt[s][c];
        }
    }
}

// ---- K4: scatter centered features into per-class compacted matrix ----
__global__ void k_scatter(const float* __restrict__ feat, const int* __restrict__ lab) {
    int n = blockIdx.x*256 + threadIdx.x;
    int g = blockIdx.y;
    int c = lab[n];
    int pos = g_segoff[n >> 8][c] + g_rank[n];
    float v = feat[(size_t)(n>>12)*1048576 + (size_t)g*4096 + (n&4095)] - g_mu[c][g];
    g_X[c][g][pos] = v;
}

// ---- K5: cov = (Xc Xc^T)/ns ----
__global__ void k_covgemm() {
    int cls = blockIdx.z, ti = blockIdx.y, tj = blockIdx.x;
    __shared__ float At[64][17], Bt[64][17];
    int t = threadIdx.x, tx = t & 15, ty = t >> 4;
    float accv[4][4] = {};
    for (int k0 = 0; k0 < KPAD; k0 += 16) {
        #pragma unroll
        for (int l = 0; l < 4; ++l) {
            int idx = t*4 + l;
            int row = idx >> 4, col = idx & 15;
            At[row][col] = g_X[cls][ti*64+row][k0+col];
            Bt[row][col] = g_X[cls][tj*64+row][k0+col];
        }
        __syncthreads();
        #pragma unroll
        for (int kk = 0; kk < 16; ++kk) {
            float a[4], b[4];
            #pragma unroll
            for (int i = 0; i < 4; ++i) a[i] = At[ty*4+i][kk];
            #pragma unroll
            for (int j = 0; j < 4; ++j) b[j] = Bt[tx*4+j][kk];
            #pragma unroll
            for (int i = 0; i < 4; ++i)
                #pragma unroll
                for (int j = 0; j < 4; ++j) accv[i][j] += a[i]*b[j];
        }
        __syncthreads();
    }
    float invns = 1.f / g_ns[cls];
    #pragma unroll
    for (int i = 0; i < 4; ++i)
        #pragma unroll
        for (int j = 0; j < 4; ++j)
            g_cov[cls][ti*64+ty*4+i][tj*64+tx*4+j] = accv[i][j]*invns;
}

// ---- K6: FUSED eigensolver (producer = Jacobi, consumer = V accumulation) ----
// Phase B: uniform 9 slots/thread (dummies hit per-thread LDS scratch), batched
// read->compute->write in chunks of 5+4 to keep ~20 ds_reads in flight.
// Disjoint groups => reordering is bitwise-identical to the serial loop.
__global__ __launch_bounds__(1024) void k_eigen() {
    extern __shared__ float smem[];
    int t = threadIdx.x;

    if (blockIdx.x < NCLS) {
        // ================= Jacobi producer =================
        float* pc  = smem;                    // 128 cosines
        float* ps  = smem + 128;              // 128 sines
        float* tri = smem + 256;              // TRI_N floats
        const int scr = 256 + TRI_N + t;      // per-thread dummy scratch (float idx)
        int cls = blockIdx.x;

        for (int L = t; L < TRI_N; L += 1024) {
            int i = (int)((sqrtf(8.f*L+1.f)-1.f)*0.5f);
            while ((i+1)*(i+2)/2 <= L) ++i;
            while (i*(i+1)/2 > L) --i;
            int j = L - i*(i+1)/2;
            tri[L] = g_cov[cls][i][j];
        }
        // uniform 9-slot register table (dummy slots flagged)
        int my_s1[9], my_s2[9];
        bool my_dum[9];
        #pragma unroll
        for (int k = 0; k < 9; ++k) {
            int gi = t + 1024*k;
            if (gi < NGROUP) {
                int s2 = (int)((sqrtf(8.f*gi+1.f)-1.f)*0.5f);
                while ((s2+1)*(s2+2)/2 <= gi) ++s2;
                while (s2*(s2+1)/2 > gi) --s2;
                my_s1[k] = gi - s2*(s2+1)/2;
                my_s2[k] = s2;
                my_dum[k] = false;
            } else {
                my_s1[k] = 0; my_s2[k] = 0; my_dum[k] = true;
            }
        }
        __syncthreads();

        for (int step = 0; step < NSTEP; ++step) {
            int r = step % NROUND;
            if (t < NPAIR) {
                int p, q; get_pair(r, t, p, q);
                float app = tri[tidx(p,p)], aqq = tri[tidx(q,q)], apq = tri[tidx(q,p)];
                float c = 1.f, s = 0.f;
                if (fabsf(apq) > 1e-30f) {
                    float theta = (aqq - app) / (2.f*apq);
                    float tt = 1.f/(fabsf(theta) + sqrtf(theta*theta + 1.f));
                    if (theta < 0.f) tt = -tt;
                    c = 1.f/sqrtf(tt*tt + 1.f);
                    s = tt*c;
                }
                pc[t] = c; ps[t] = s;
                PackCS pk; pk.f = make_float2(c, s);
                __hip_atomic_store(&g_rotlog[cls][step][t], pk.u,
                                   __ATOMIC_RELAXED, __HIP_MEMORY_SCOPE_AGENT);
            }
            __syncthreads();   // rotlog stores drained; pc/ps visible
            if (t == 0) {
                __hip_atomic_store(&g_step[cls*FLAGSTRIDE], step+1,
                                   __ATOMIC_RELAXED, __HIP_MEMORY_SCOPE_AGENT);
            }

            #pragma unroll
            for (int chunk = 0; chunk < 2; ++chunk) {
                const int base = chunk ? 5 : 0;
                const int cnt  = chunk ? 4 : 5;
                float B[5][4]; int adr[5][4];
                float r1c[5], r1s[5], r2c[5], r2s[5];
                bool dia[5];
                #pragma unroll
                for (int u = 0; u < 5; ++u) {
                    if (u >= cnt) break;
                    int slot = base + u;
                    int s1 = my_s1[slot], s2 = my_s2[slot];
                    dia[u] = (s1 == s2);
                    r1c[u] = pc[s1]; r1s[u] = ps[s1];
                    r2c[u] = pc[s2]; r2s[u] = ps[s2];
                    int p1, q1; get_pair(r, s1, p1, q1);
                    int p2, q2; get_pair(r, s2, p2, q2);
                    if (my_dum[slot]) {
                        adr[u][0] = scr; adr[u][1] = scr; adr[u][2] = scr; adr[u][3] = scr;
                    } else if (dia[u]) {
                        adr[u][0] = tidx(p1,p1); adr[u][1] = tidx(q1,p1);
                        adr[u][2] = adr[u][1];   adr[u][3] = tidx(q1,q1);
                    } else {
                        adr[u][0] = tidx2(p1,p2); adr[u][1] = tidx2(p1,q2);
                        adr[u][2] = tidx2(q1,p2); adr[u][3] = tidx2(q1,q2);
                    }
                    B[u][0] = smem[adr[u][0] + (my_dum[slot] ? 0 : 256)];
                    B[u][1] = smem[adr[u][1] + (my_dum[slot] ? 0 : 256)];
                    B[u][2] = smem[adr[u][2] + (my_dum[slot] ? 0 : 256)];
                    B[u][3] = smem[adr[u][3] + (my_dum[slot] ? 0 : 256)];
                    // normalize addresses to absolute smem index for the write phase
                    adr[u][0] += my_dum[slot] ? 0 : 256;
                    adr[u][1] += my_dum[slot] ? 0 : 256;
                    adr[u][2] += my_dum[slot] ? 0 : 256;
                    adr[u][3] += my_dum[slot] ? 0 : 256;
                }
                #pragma unroll
                for (int u = 0; u < 5; ++u) {
                    if (u >= cnt) break;
                    float c1 = r1c[u], sv1 = r1s[u];
                    if (dia[u]) {
                        float app = B[u][0], apq = B[u][1], aqq = B[u][3];
                        float napp = c1*c1*app - 2.f*c1*sv1*apq + sv1*sv1*aqq;
                        float naqq = sv1*sv1*app + 2.f*c1*sv1*apq + c1*c1*aqq;
                        smem[adr[u][0]] = napp;
                        smem[adr[u][3]] = naqq;
                        smem[adr[u][1]] = 0.f;
                    } else {
                        float c2 = r2c[u], sv2 = r2s[u];
                        float B00 = B[u][0], B01 = B[u][1], B10 = B[u][2], B11 = B[u][3];
                        float X00 = c1*B00 - sv1*B10, X01 = c1*B01 - sv1*B11;
                        float X10 = sv1*B00 + c1*B10, X11 = sv1*B01 + c1*B11;
                        smem[adr[u][0]] = c2*X00 - sv2*X01;
                        smem[adr[u][1]] = sv2*X00 + c2*X01;
                        smem[adr[u][2]] = c2*X10 - sv2*X11;
                        smem[adr[u][3]] = sv2*X10 + c2*X11;
                    }
                }
            }
            __syncthreads();
        }
        for (int f = t; f < FDIM; f += 1024)
            g_eval[cls][f] = tri[tidx(f,f)];
    } else {
        // ================= eigenvector consumer =================
        float* lc = smem;
        float* ls = smem + 128;
        float* st = smem + 256;       // 256 x VST state (64 V-columns)
        int rb = blockIdx.x - NCLS;
        int cls = rb >> 2;
        int ibase = (rb & 3) * 64;

        for (int idx = t; idx < 256*64; idx += 1024) {
            int p = idx >> 6, col = idx & 63;
            st[p*VST + col] = (p == ibase + col) ? 1.f : 0.f;
        }
        __syncthreads();

        int s0 = t >> 5;
        int cp = t & 31;
        for (int step = 0; step < NSTEP; ++step) {
            int r = step % NROUND;
            if (t == 0) {
                while (__hip_atomic_load(&g_step[cls*FLAGSTRIDE], __ATOMIC_RELAXED,
                                         __HIP_MEMORY_SCOPE_AGENT) <= step)
                    __builtin_amdgcn_s_sleep(2);
            }
            __syncthreads();
            if (t < NPAIR) {
                PackCS pk;
                pk.u = __hip_atomic_load(&g_rotlog[cls][step][t],
                                         __ATOMIC_RELAXED, __HIP_MEMORY_SCOPE_AGENT);
                lc[t] = pk.f.x; ls[t] = pk.f.y;
            }
            __syncthreads();
            float2 xv[4], yv[4];
            float cv[4], sv[4];
            int pa[4], qa[4];
            #pragma unroll
            for (int w = 0; w < 4; ++w) {
                int s = s0 + 32*w;
                cv[w] = lc[s]; sv[w] = ls[s];
                get_pair(r, s, pa[w], qa[w]);
                xv[w] = *(float2*)&st[pa[w]*VST + 2*cp];
                yv[w] = *(float2*)&st[qa[w]*VST + 2*cp];
            }
            #pragma unroll
            for (int w = 0; w < 4; ++w) {
                float2 nx, ny;
                nx.x = cv[w]*xv[w].x - sv[w]*yv[w].x;
                nx.y = cv[w]*xv[w].y - sv[w]*yv[w].y;
                ny.x = sv[w]*xv[w].x + cv[w]*yv[w].x;
                ny.y = sv[w]*xv[w].y + cv[w]*yv[w].y;
                *(float2*)&st[pa[w]*VST + 2*cp] = nx;
                *(float2*)&st[qa[w]*VST + 2*cp] = ny;
            }
        }
        __syncthreads();
        for (int idx = t; idx < 256*32; idx += 1024) {
            int f = idx >> 5, c2 = idx & 31;
            float2 v = *(float2*)&st[f*VST + 2*c2];
            *(float2*)&g_Vt[cls][f][ibase + 2*c2] = v;
        }
    }
}

// ---- K8: sort eigenpairs descending (deterministic rank), build W ----
__global__ void k_sort() {
    __shared__ float ev[256];
    __shared__ int rk[256];
    int cls = blockIdx.x, t = threadIdx.x;
    ev[t] = g_eval[cls][t];
    __syncthreads();
    float mine = ev[t];
    int r = 0;
    for (int f = 0; f < 256; ++f) {
        float o = ev[f];
        if (o > mine || (o == mine && f < t)) ++r;
    }
    rk[t] = r;
    __syncthreads();
    for (int f = 0; f < 256; ++f)
        g_W[cls][rk[f]][t] = g_Vt[cls][f][t];
}

// ---- K10: M[c] = proj @ W[c]   (D x F) ----
__global__ void k_mgemm(const float* __restrict__ pm) {
    int cls = blockIdx.z, dt = blockIdx.y, gt = blockIdx.x;
    __shared__ float At[64][17], Bt[16][65];
    int t = threadIdx.x, tx = t & 15, ty = t >> 4;
    float accv[4][4] = {};
    for (int k0 = 0; k0 < FDIM; k0 += 16) {
        #pragma unroll
        for (int l = 0; l < 4; ++l) {
            int idx = t*4 + l;
            int row = idx >> 4, col = idx & 15;
            At[row][col] = pm[(size_t)(dt*64+row)*FDIM + k0 + col];
        }
        #pragma unroll
        for (int l = 0; l < 4; ++l) {
            int idx = t*4 + l;
            int row = idx >> 6, col = idx & 63;
            Bt[row][col] = g_W[cls][k0+row][gt*64+col];
        }
        __syncthreads();
        #pragma unroll
        for (int kk = 0; kk < 16; ++kk) {
            float a[4], b[4];
            #pragma unroll
            for (int i = 0; i < 4; ++i) a[i] = At[ty*4+i][kk];
            #pragma unroll
            for (int j = 0; j < 4; ++j) b[j] = Bt[kk][tx*4+j];
            #pragma unroll
            for (int i = 0; i < 4; ++i)
                #pragma unroll
                for (int j = 0; j < 4; ++j) accv[i][j] += a[i]*b[j];
        }
        __syncthreads();
    }
    #pragma unroll
    for (int i = 0; i < 4; ++i)
        #pragma unroll
        for (int j = 0; j < 4; ++j)
            g_M[cls][dt*64+ty*4+i][gt*64+tx*4+j] = accv[i][j];
}

// ---- K11: fv = M[c] @ Xc, accumulate moments m1..m4 over columns ----
__global__ void k_fvmom() {
    int cls = blockIdx.y, dt = blockIdx.x;
    __shared__ float Mt[64][17], Xt[16][65];
    __shared__ float red[64][16];
    int t = threadIdx.x, tx = t & 15, ty = t >> 4;
    float mm[4][4] = {};
    for (int kt = 0; kt < KPAD; kt += 64) {
        float accv[4][4] = {};
        for (int g0 = 0; g0 < FDIM; g0 += 16) {
            #pragma unroll
            for (int l = 0; l < 4; ++l) {
                int idx = t*4 + l;
                int row = idx >> 4, col = idx & 15;
                Mt[row][col] = g_M[cls][dt*64+row][g0+col];
            }
            #pragma unroll
            for (int l = 0; l < 4; ++l) {
                int idx = t*4 + l;
                int row = idx >> 6, col = idx & 63;
                Xt[row][col] = g_X[cls][g0+row][kt+col];
            }
            __syncthreads();
            #pragma unroll
            for (int kk = 0; kk < 16; ++kk) {
                float a[4], b[4];
                #pragma unroll
                for (int i = 0; i < 4; ++i) a[i] = Mt[ty*4+i][kk];
                #pragma unroll
                for (int j = 0; j < 4; ++j) b[j] = Xt[kk][tx*4+j];
                #pragma unroll
                for (int i = 0; i < 4; ++i)
                    #pragma unroll
                    for (int j = 0; j < 4; ++j) accv[i][j] += a[i]*b[j];
            }
            __syncthreads();
        }
        #pragma unroll
        for (int i = 0; i < 4; ++i)
            #pragma unroll
            for (int j = 0; j < 4; ++j) {
                float v = accv[i][j], v2 = v*v;
                mm[0][i] += v; mm[1][i] += v2; mm[2][i] += v2*v; mm[3][i] += v2*v2;
            }
    }
    #pragma unroll
    for (int m = 0; m < 4; ++m) {
        __syncthreads();
        #pragma unroll
        for (int i = 0; i < 4; ++i) red[ty*4+i][tx] = mm[m][i];
        __syncthreads();
        if (t < 64) {
            float s = 0.f;
            #pragma unroll
            for (int x = 0; x < 16; ++x) s += red[t][x];
            g_mom[cls][dt*64 + t][m] = s;
        }
    }
}

// ---- K12: kurtosis, clip, weighted mean -> loss ----
__global__ __launch_bounds__(1024) void k_loss(float* __restrict__ out) {
    __shared__ float red[1024];
    int t = threadIdx.x;
    float sum = 0.f;
    for (int id = t; id < NCLS*DDIR; id += 1024) {
        int c = id >> 10, d = id & 1023;
        float cntv = g_cntf[c];
        if (cntv > 0.f) {
            float invns = 1.f / g_ns[c];
            float m1 = g_mom[c][d][0]*invns;
            float m2 = g_mom[c][d][1]*invns;
            float m3 = g_mom[c][d][2]*invns;
            float m4 = g_mom[c][d][3]*invns;
            float var = fmaxf(m2 - m1*m1, 1e-16f);
            float m4c = -3.f*m1*m1*m1*m1 + 6.f*m2*m1*m1 - 4.f*m3*m1 + m4;
            float kurt = m4c/(var*var) - 3.f;
            kurt = fminf(fmaxf(kurt, -3.f), 3.f);
            sum += kurt*kurt;
        }
    }
    red[t] = sum;
    __syncthreads();
    for (int off = 512; off > 0; off >>= 1) {
        if (t < off) red[t] += red[t+off];
        __syncthreads();
    }
    if (t == 0) {
        float na = 0.f;
        for (int c = 0; c < NCLS; ++c) na += (g_cntf[c] > 0.f) ? 1.f : 0.f;
        na = fmaxf(na, 1.f);
        out[0] = red[0] / ((float)DDIR * na);
    }
}

extern "C" void kernel_launch(void* const* d_in, const int* in_sizes, int n_in,
                              void* d_out, int out_size, void* d_ws, size_t ws_size,
                              hipStream_t stream) {
    const float* feat = (const float*)d_in[0];
    const int*   lab  = (const int*)d_in[1];
    const float* pm   = (const float*)d_in[2];
    float* out = (float*)d_out;

    // pc/ps (256) + tri (TRI_N) + per-thread dummy scratch (1024)
    const int eig_lds = (256 + TRI_N + 1024) * 4 + 64;   // ~136.8 KB

    (void)hipFuncSetAttribute((const void*)k_eigen,
        hipFuncAttributeMaxDynamicSharedMemorySize, eig_lds);

    hipLaunchKernelGGL(k_zero, dim3(3648), dim3(1024), 0, stream);
    hipLaunchKernelGGL(k_sums, dim3(256), dim3(256), 0, stream, feat, lab);
    hipLaunchKernelGGL(k_musetup, dim3(1), dim3(256), 0, stream);
    hipLaunchKernelGGL(k_rank, dim3(NSEG), dim3(256), 0, stream, lab);
    hipLaunchKernelGGL(k_segscan, dim3(1), dim3(64), 0, stream);
    hipLaunchKernelGGL(k_scatter, dim3(32, 256), dim3(256), 0, stream, feat, lab);
    hipLaunchKernelGGL(k_covgemm, dim3(4, 4, NCLS), dim3(256), 0, stream);
    hipLaunchKernelGGL(k_eigen, dim3(NCLS + NCLS*4), dim3(1024), eig_lds, stream);
    hipLaunchKernelGGL(k_sort, dim3(NCLS), dim3(256), 0, stream);
    hipLaunchKernelGGL(k_mgemm, dim3(4, 16, NCLS), dim3(256), 0, stream, pm);
    hipLaunchKernelGGL(k_fvmom, dim3(16, NCLS), dim3(256), 0, stream);
    hipLaunchKernelGGL(k_loss, dim3(1), dim3(1024), 0, stream, out);
}

// Round 7
// 7018.954 us; speedup vs baseline: 1.3121x; 1.3121x over previous
//
#include <hip/hip_runtime.h>
#include <math.h>

// Problem constants
#define NCLS 19
#define FDIM 256
#define DDIR 1024
#define NPIX 8192
#define KPAD 768            // per-class compacted-column padding (max n_c ~ 500)
#define NSWEEP 5
#define NROUND 255
#define NSTEP (NSWEEP*NROUND)
#define NPAIR 128
#define TRI_N 32896         // 256*257/2
#define NOFF 8128           // 128*127/2 off-diagonal group pairs (s1<s2)
#define NSEG 32             // 8192 / 256 label segments
#define VST 66              // replay V-state row stride (64 + 2 pad)
#define FLAGSTRIDE 16       // pad step-flags to 64B lines

// ---- device-global workspace ----
__device__ float g_sum[NCLS][FDIM];
__device__ float g_cntf[NCLS];
__device__ float g_ns[NCLS];
__device__ float g_mu[NCLS][FDIM];
__device__ int   g_rank[NPIX];
__device__ int   g_segcnt[NSEG][NCLS];
__device__ int   g_segoff[NSEG][NCLS];
__device__ float g_X[NCLS][FDIM][KPAD];
__device__ float g_cov[NCLS][FDIM][FDIM];
__device__ unsigned long long g_rotlog[NCLS][NSTEP][NPAIR];  // packed (c,s)
__device__ int   g_step[NCLS*FLAGSTRIDE];
__device__ float g_eval[NCLS][FDIM];
__device__ float g_Vt[NCLS][FDIM][FDIM];
__device__ float g_W[NCLS][FDIM][FDIM];
__device__ float g_M[NCLS][DDIR][FDIM];
__device__ float g_mom[NCLS][DDIR][4];

union PackCS { float2 f; unsigned long long u; };

// round-robin tournament pairing: 255 fixed, 0..254 rotate
__device__ __forceinline__ void get_pair(int r, int s, int& p, int& q) {
    int a, b;
    if (s == 0) { a = NROUND; b = r; }
    else {
        a = r + s; if (a >= NROUND) a -= NROUND;
        b = r - s; if (b < 0) b += NROUND;
    }
    p = min(a, b); q = max(a, b);
}

__device__ __forceinline__ int tidx(int i, int j) { return ((i*(i+1))>>1) + j; } // i>=j
__device__ __forceinline__ int tidx2(int a, int b) { return a >= b ? tidx(a,b) : tidx(b,a); }

// ---- K0: zero compacted buffer + flags + segment counters ----
__global__ __launch_bounds__(1024) void k_zero() {
    int idx = blockIdx.x*blockDim.x + threadIdx.x;
    const int total = NCLS*FDIM*KPAD;
    float* x = &g_X[0][0][0];
    for (int i = idx; i < total; i += gridDim.x*blockDim.x) x[i] = 0.f;
    if (idx < NCLS*FLAGSTRIDE) g_step[idx] = 0;
    if (idx < NSEG*NCLS) (&g_segcnt[0][0])[idx] = 0;
}

// ---- K1: per-class sums per feature + counts (block = feature f) ----
__global__ void k_sums(const float* __restrict__ feat, const int* __restrict__ lab) {
    __shared__ float acc[NCLS][256];
    __shared__ float cnt[NCLS][256];
    int t = threadIdx.x;
    int f = blockIdx.x;
    for (int c = 0; c < NCLS; ++c) { acc[c][t] = 0.f; cnt[c][t] = 0.f; }
    for (int j = 0; j < NPIX/256; ++j) {
        int n = t + 256*j;
        int b = n >> 12, hw = n & 4095;
        float v = feat[(size_t)b*1048576 + (size_t)f*4096 + hw];
        int c = lab[n];
        acc[c][t] += v;
        cnt[c][t] += 1.f;
    }
    __syncthreads();
    for (int off = 128; off > 0; off >>= 1) {
        if (t < off)
            for (int c = 0; c < NCLS; ++c) {
                acc[c][t] += acc[c][t+off];
                cnt[c][t] += cnt[c][t+off];
            }
        __syncthreads();
    }
    if (t < NCLS) {
        g_sum[t][f] = acc[t][0];
        if (f == 0) g_cntf[t] = cnt[t][0];
    }
}

// ---- K2: ns and mu ----
__global__ void k_musetup() {
    int t = threadIdx.x;
    if (t < NCLS) g_ns[t] = fmaxf(g_cntf[t], 1.f);
    __syncthreads();
    for (int c = 0; c < NCLS; ++c)
        g_mu[c][t] = g_sum[c][t] / g_ns[c];
}

// ---- K3a: deterministic per-segment rank + per-segment class counts ----
__global__ void k_rank(const int* __restrict__ lab) {
    __shared__ int sl[256];
    int seg = blockIdx.x, t = threadIdx.x;
    int n = seg*256 + t;
    int c = lab[n];
    sl[t] = c;
    __syncthreads();
    int rnk = 0, tot = 0;
    for (int i = 0; i < 256; ++i) {
        int e = sl[i];
        if (e == c) { tot += 1; if (i < t) rnk += 1; }
    }
    g_rank[n] = rnk;
    if (rnk == 0) g_segcnt[seg][c] = tot;
}

// ---- K3b: exclusive scan of segment counts per class ----
__global__ void k_segscan() {
    int c = threadIdx.x;
    if (c < NCLS) {
        int run = 0;
        for (int s = 0; s < NSEG; ++s) {
            g_segoff[s][c] = run;
            run += g_segcnt[s][c];
        }
    }
}

// ---- K4: scatter centered features into per-class compacted matrix ----
__global__ void k_scatter(const float* __restrict__ feat, const int* __restrict__ lab) {
    int n = blockIdx.x*256 + threadIdx.x;
    int g = blockIdx.y;
    int c = lab[n];
    int pos = g_segoff[n >> 8][c] + g_rank[n];
    float v = feat[(size_t)(n>>12)*1048576 + (size_t)g*4096 + (n&4095)] - g_mu[c][g];
    g_X[c][g][pos] = v;
}

// ---- K5: cov = (Xc Xc^T)/ns ----
__global__ void k_covgemm() {
    int cls = blockIdx.z, ti = blockIdx.y, tj = blockIdx.x;
    __shared__ float At[64][17], Bt[64][17];
    int t = threadIdx.x, tx = t & 15, ty = t >> 4;
    float accv[4][4] = {};
    for (int k0 = 0; k0 < KPAD; k0 += 16) {
        #pragma unroll
        for (int l = 0; l < 4; ++l) {
            int idx = t*4 + l;
            int row = idx >> 4, col = idx & 15;
            At[row][col] = g_X[cls][ti*64+row][k0+col];
            Bt[row][col] = g_X[cls][tj*64+row][k0+col];
        }
        __syncthreads();
        #pragma unroll
        for (int kk = 0; kk < 16; ++kk) {
            float a[4], b[4];
            #pragma unroll
            for (int i = 0; i < 4; ++i) a[i] = At[ty*4+i][kk];
            #pragma unroll
            for (int j = 0; j < 4; ++j) b[j] = Bt[tx*4+j][kk];
            #pragma unroll
            for (int i = 0; i < 4; ++i)
                #pragma unroll
                for (int j = 0; j < 4; ++j) accv[i][j] += a[i]*b[j];
        }
        __syncthreads();
    }
    float invns = 1.f / g_ns[cls];
    #pragma unroll
    for (int i = 0; i < 4; ++i)
        #pragma unroll
        for (int j = 0; j < 4; ++j)
            g_cov[cls][ti*64+ty*4+i][tj*64+tx*4+j] = accv[i][j]*invns;
}

// ---- K6: FUSED eigensolver (producer = Jacobi, consumer = V accumulation) ----
// Phase A (128 threads): compute rotations AND apply the diagonal 2x2 update
// (those cells are touched by no off-diag group -> hazard-free, verbatim
// expressions -> bitwise identical). Phase B: 8128 off-diag groups, serial
// round-5 loop, max 8/thread (straggler was 9). rotlog store issued AFTER
// the A->B barrier from registers so its LLC drain overlaps phase B; step
// flag published at end-of-step barrier.
__global__ __launch_bounds__(1024) void k_eigen() {
    extern __shared__ float smem[];
    int t = threadIdx.x;

    if (blockIdx.x < NCLS) {
        // ================= Jacobi producer =================
        float* pc  = smem;            // 128 cosines
        float* ps  = smem + 128;      // 128 sines
        float* tri = smem + 256;      // TRI_N floats
        int cls = blockIdx.x;

        for (int L = t; L < TRI_N; L += 1024) {
            int i = (int)((sqrtf(8.f*L+1.f)-1.f)*0.5f);
            while ((i+1)*(i+2)/2 <= L) ++i;
            while (i*(i+1)/2 > L) --i;
            int j = L - i*(i+1)/2;
            tri[L] = g_cov[cls][i][j];
        }
        // off-diagonal (s1<s2) register table: 8128 groups, <=8 per thread
        int my_s1[8], my_s2[8];
        int nmy = 0;
        #pragma unroll
        for (int k = 0; k < 8; ++k) {
            int gi = t + 1024*k;
            if (gi < NOFF) {
                int s2 = (int)((1.f + sqrtf(1.f + 8.f*gi))*0.5f);
                while (s2*(s2-1)/2 > gi) --s2;
                while ((s2+1)*s2/2 <= gi) ++s2;
                my_s1[nmy] = gi - s2*(s2-1)/2;
                my_s2[nmy] = s2;
                ++nmy;
            }
        }
        __syncthreads();

        for (int step = 0; step < NSTEP; ++step) {
            int r = step % NROUND;
            float cA = 1.f, sA = 0.f;
            if (t < NPAIR) {
                int p, q; get_pair(r, t, p, q);
                float app = tri[tidx(p,p)], aqq = tri[tidx(q,q)], apq = tri[tidx(q,p)];
                float c = 1.f, s = 0.f;
                if (fabsf(apq) > 1e-30f) {
                    float theta = (aqq - app) / (2.f*apq);
                    float tt = 1.f/(fabsf(theta) + sqrtf(theta*theta + 1.f));
                    if (theta < 0.f) tt = -tt;
                    c = 1.f/sqrtf(tt*tt + 1.f);
                    s = tt*c;
                }
                pc[t] = c; ps[t] = s;
                cA = c; sA = s;
                // diagonal 2x2 update (verbatim from old diag-group branch)
                float napp = c*c*app - 2.f*c*s*apq + s*s*aqq;
                float naqq = s*s*app + 2.f*c*s*apq + c*c*aqq;
                tri[tidx(p,p)] = napp;
                tri[tidx(q,q)] = naqq;
                tri[tidx(q,p)] = 0.f;
            }
            __syncthreads();   // pc/ps + diag updates visible; no global op pending
            if (t < NPAIR) {
                PackCS pk; pk.f = make_float2(cA, sA);
                __hip_atomic_store(&g_rotlog[cls][step][t], pk.u,
                                   __ATOMIC_RELAXED, __HIP_MEMORY_SCOPE_AGENT);
            }

            for (int g = 0; g < nmy; ++g) {
                int s1 = my_s1[g], s2 = my_s2[g];
                float c1 = pc[s1], sv1 = ps[s1];
                float c2 = pc[s2], sv2 = ps[s2];
                int p1, q1; get_pair(r, s1, p1, q1);
                int p2, q2; get_pair(r, s2, p2, q2);
                float B00 = tri[tidx2(p1,p2)], B01 = tri[tidx2(p1,q2)];
                float B10 = tri[tidx2(q1,p2)], B11 = tri[tidx2(q1,q2)];
                float X00 = c1*B00 - sv1*B10, X01 = c1*B01 - sv1*B11;
                float X10 = sv1*B00 + c1*B10, X11 = sv1*B01 + c1*B11;
                tri[tidx2(p1,p2)] = c2*X00 - sv2*X01;
                tri[tidx2(p1,q2)] = sv2*X00 + c2*X01;
                tri[tidx2(q1,p2)] = c2*X10 - sv2*X11;
                tri[tidx2(q1,q2)] = sv2*X10 + c2*X11;
            }
            __syncthreads();   // drains rotlog store (vmcnt0) + all LDS
            if (t == 0) {
                __hip_atomic_store(&g_step[cls*FLAGSTRIDE], step+1,
                                   __ATOMIC_RELAXED, __HIP_MEMORY_SCOPE_AGENT);
            }
        }
        for (int f = t; f < FDIM; f += 1024)
            g_eval[cls][f] = tri[tidx(f,f)];
    } else {
        // ================= eigenvector consumer =================
        float* lc = smem;
        float* ls = smem + 128;
        float* st = smem + 256;       // 256 x VST state (64 V-columns)
        int rb = blockIdx.x - NCLS;
        int cls = rb >> 2;
        int ibase = (rb & 3) * 64;

        for (int idx = t; idx < 256*64; idx += 1024) {
            int p = idx >> 6, col = idx & 63;
            st[p*VST + col] = (p == ibase + col) ? 1.f : 0.f;
        }
        __syncthreads();

        int s0 = t >> 5;
        int cp = t & 31;
        for (int step = 0; step < NSTEP; ++step) {
            int r = step % NROUND;
            if (t == 0) {
                while (__hip_atomic_load(&g_step[cls*FLAGSTRIDE], __ATOMIC_RELAXED,
                                         __HIP_MEMORY_SCOPE_AGENT) <= step)
                    __builtin_amdgcn_s_sleep(2);
            }
            __syncthreads();
            if (t < NPAIR) {
                PackCS pk;
                pk.u = __hip_atomic_load(&g_rotlog[cls][step][t],
                                         __ATOMIC_RELAXED, __HIP_MEMORY_SCOPE_AGENT);
                lc[t] = pk.f.x; ls[t] = pk.f.y;
            }
            __syncthreads();
            float2 xv[4], yv[4];
            float cv[4], sv[4];
            int pa[4], qa[4];
            #pragma unroll
            for (int w = 0; w < 4; ++w) {
                int s = s0 + 32*w;
                cv[w] = lc[s]; sv[w] = ls[s];
                get_pair(r, s, pa[w], qa[w]);
                xv[w] = *(float2*)&st[pa[w]*VST + 2*cp];
                yv[w] = *(float2*)&st[qa[w]*VST + 2*cp];
            }
            #pragma unroll
            for (int w = 0; w < 4; ++w) {
                float2 nx, ny;
                nx.x = cv[w]*xv[w].x - sv[w]*yv[w].x;
                nx.y = cv[w]*xv[w].y - sv[w]*yv[w].y;
                ny.x = sv[w]*xv[w].x + cv[w]*yv[w].x;
                ny.y = sv[w]*xv[w].y + cv[w]*yv[w].y;
                *(float2*)&st[pa[w]*VST + 2*cp] = nx;
                *(float2*)&st[qa[w]*VST + 2*cp] = ny;
            }
        }
        __syncthreads();
        for (int idx = t; idx < 256*32; idx += 1024) {
            int f = idx >> 5, c2 = idx & 31;
            float2 v = *(float2*)&st[f*VST + 2*c2];
            *(float2*)&g_Vt[cls][f][ibase + 2*c2] = v;
        }
    }
}

// ---- K8: sort eigenpairs descending (deterministic rank), build W ----
__global__ void k_sort() {
    __shared__ float ev[256];
    __shared__ int rk[256];
    int cls = blockIdx.x, t = threadIdx.x;
    ev[t] = g_eval[cls][t];
    __syncthreads();
    float mine = ev[t];
    int r = 0;
    for (int f = 0; f < 256; ++f) {
        float o = ev[f];
        if (o > mine || (o == mine && f < t)) ++r;
    }
    rk[t] = r;
    __syncthreads();
    for (int f = 0; f < 256; ++f)
        g_W[cls][rk[f]][t] = g_Vt[cls][f][t];
}

// ---- K10: M[c] = proj @ W[c]   (D x F) ----
__global__ void k_mgemm(const float* __restrict__ pm) {
    int cls = blockIdx.z, dt = blockIdx.y, gt = blockIdx.x;
    __shared__ float At[64][17], Bt[16][65];
    int t = threadIdx.x, tx = t & 15, ty = t >> 4;
    float accv[4][4] = {};
    for (int k0 = 0; k0 < FDIM; k0 += 16) {
        #pragma unroll
        for (int l = 0; l < 4; ++l) {
            int idx = t*4 + l;
            int row = idx >> 4, col = idx & 15;
            At[row][col] = pm[(size_t)(dt*64+row)*FDIM + k0 + col];
        }
        #pragma unroll
        for (int l = 0; l < 4; ++l) {
            int idx = t*4 + l;
            int row = idx >> 6, col = idx & 63;
            Bt[row][col] = g_W[cls][k0+row][gt*64+col];
        }
        __syncthreads();
        #pragma unroll
        for (int kk = 0; kk < 16; ++kk) {
            float a[4], b[4];
            #pragma unroll
            for (int i = 0; i < 4; ++i) a[i] = At[ty*4+i][kk];
            #pragma unroll
            for (int j = 0; j < 4; ++j) b[j] = Bt[kk][tx*4+j];
            #pragma unroll
            for (int i = 0; i < 4; ++i)
                #pragma unroll
                for (int j = 0; j < 4; ++j) accv[i][j] += a[i]*b[j];
        }
        __syncthreads();
    }
    #pragma unroll
    for (int i = 0; i < 4; ++i)
        #pragma unroll
        for (int j = 0; j < 4; ++j)
            g_M[cls][dt*64+ty*4+i][gt*64+tx*4+j] = accv[i][j];
}

// ---- K11: fv = M[c] @ Xc, accumulate moments m1..m4 over columns ----
__global__ void k_fvmom() {
    int cls = blockIdx.y, dt = blockIdx.x;
    __shared__ float Mt[64][17], Xt[16][65];
    __shared__ float red[64][16];
    int t = threadIdx.x, tx = t & 15, ty = t >> 4;
    float mm[4][4] = {};
    for (int kt = 0; kt < KPAD; kt += 64) {
        float accv[4][4] = {};
        for (int g0 = 0; g0 < FDIM; g0 += 16) {
            #pragma unroll
            for (int l = 0; l < 4; ++l) {
                int idx = t*4 + l;
                int row = idx >> 4, col = idx & 15;
                Mt[row][col] = g_M[cls][dt*64+row][g0+col];
            }
            #pragma unroll
            for (int l = 0; l < 4; ++l) {
                int idx = t*4 + l;
                int row = idx >> 6, col = idx & 63;
                Xt[row][col] = g_X[cls][g0+row][kt+col];
            }
            __syncthreads();
            #pragma unroll
            for (int kk = 0; kk < 16; ++kk) {
                float a[4], b[4];
                #pragma unroll
                for (int i = 0; i < 4; ++i) a[i] = Mt[ty*4+i][kk];
                #pragma unroll
                for (int j = 0; j < 4; ++j) b[j] = Xt[kk][tx*4+j];
                #pragma unroll
                for (int i = 0; i < 4; ++i)
                    #pragma unroll
                    for (int j = 0; j < 4; ++j) accv[i][j] += a[i]*b[j];
            }
            __syncthreads();
        }
        #pragma unroll
        for (int i = 0; i < 4; ++i)
            #pragma unroll
            for (int j = 0; j < 4; ++j) {
                float v = accv[i][j], v2 = v*v;
                mm[0][i] += v; mm[1][i] += v2; mm[2][i] += v2*v; mm[3][i] += v2*v2;
            }
    }
    #pragma unroll
    for (int m = 0; m < 4; ++m) {
        __syncthreads();
        #pragma unroll
        for (int i = 0; i < 4; ++i) red[ty*4+i][tx] = mm[m][i];
        __syncthreads();
        if (t < 64) {
            float s = 0.f;
            #pragma unroll
            for (int x = 0; x < 16; ++x) s += red[t][x];
            g_mom[cls][dt*64 + t][m] = s;
        }
    }
}

// ---- K12: kurtosis, clip, weighted mean -> loss ----
__global__ __launch_bounds__(1024) void k_loss(float* __restrict__ out) {
    __shared__ float red[1024];
    int t = threadIdx.x;
    float sum = 0.f;
    for (int id = t; id < NCLS*DDIR; id += 1024) {
        int c = id >> 10, d = id & 1023;
        float cntv = g_cntf[c];
        if (cntv > 0.f) {
            float invns = 1.f / g_ns[c];
            float m1 = g_mom[c][d][0]*invns;
            float m2 = g_mom[c][d][1]*invns;
            float m3 = g_mom[c][d][2]*invns;
            float m4 = g_mom[c][d][3]*invns;
            float var = fmaxf(m2 - m1*m1, 1e-16f);
            float m4c = -3.f*m1*m1*m1*m1 + 6.f*m2*m1*m1 - 4.f*m3*m1 + m4;
            float kurt = m4c/(var*var) - 3.f;
            kurt = fminf(fmaxf(kurt, -3.f), 3.f);
            sum += kurt*kurt;
        }
    }
    red[t] = sum;
    __syncthreads();
    for (int off = 512; off > 0; off >>= 1) {
        if (t < off) red[t] += red[t+off];
        __syncthreads();
    }
    if (t == 0) {
        float na = 0.f;
        for (int c = 0; c < NCLS; ++c) na += (g_cntf[c] > 0.f) ? 1.f : 0.f;
        na = fmaxf(na, 1.f);
        out[0] = red[0] / ((float)DDIR * na);
    }
}

extern "C" void kernel_launch(void* const* d_in, const int* in_sizes, int n_in,
                              void* d_out, int out_size, void* d_ws, size_t ws_size,
                              hipStream_t stream) {
    const float* feat = (const float*)d_in[0];
    const int*   lab  = (const int*)d_in[1];
    const float* pm   = (const float*)d_in[2];
    float* out = (float*)d_out;

    const int eig_lds = (256 + TRI_N) * 4 + 64;

    (void)hipFuncSetAttribute((const void*)k_eigen,
        hipFuncAttributeMaxDynamicSharedMemorySize, eig_lds);

    hipLaunchKernelGGL(k_zero, dim3(3648), dim3(1024), 0, stream);
    hipLaunchKernelGGL(k_sums, dim3(256), dim3(256), 0, stream, feat, lab);
    hipLaunchKernelGGL(k_musetup, dim3(1), dim3(256), 0, stream);
    hipLaunchKernelGGL(k_rank, dim3(NSEG), dim3(256), 0, stream, lab);
    hipLaunchKernelGGL(k_segscan, dim3(1), dim3(64), 0, stream);
    hipLaunchKernelGGL(k_scatter, dim3(32, 256), dim3(256), 0, stream, feat, lab);
    hipLaunchKernelGGL(k_covgemm, dim3(4, 4, NCLS), dim3(256), 0, stream);
    hipLaunchKernelGGL(k_eigen, dim3(NCLS + NCLS*4), dim3(1024), eig_lds, stream);
    hipLaunchKernelGGL(k_sort, dim3(NCLS), dim3(256), 0, stream);
    hipLaunchKernelGGL(k_mgemm, dim3(4, 16, NCLS), dim3(256), 0, stream, pm);
    hipLaunchKernelGGL(k_fvmom, dim3(16, NCLS), dim3(256), 0, stream);
    hipLaunchKernelGGL(k_loss, dim3(1), dim3(1024), 0, stream, out);
}

// Round 8
// 6941.465 us; speedup vs baseline: 1.3268x; 1.0112x over previous
//
#include <hip/hip_runtime.h>
#include <math.h>

// Problem constants
#define NCLS 19
#define FDIM 256
#define DDIR 1024
#define NPIX 8192
#define KPAD 768            // per-class compacted-column padding (max n_c ~ 500)
#define NSWEEP 5
#define NROUND 255
#define NSTEP (NSWEEP*NROUND)
#define NPAIR 128
#define TRI_N 32896         // 256*257/2
#define NOFF 8128           // 128*127/2 off-diagonal group pairs (s1<s2)
#define NSEG 32             // 8192 / 256 label segments
#define VST 66              // replay V-state row stride (64 + 2 pad)
#define FLAGSTRIDE 16       // pad step-flags to 64B lines

// ---- device-global workspace ----
__device__ float g_cntf[NCLS];
__device__ float g_ns[NCLS];
__device__ float g_mu[NCLS][FDIM];
__device__ int   g_rank[NPIX];
__device__ int   g_segcnt[NSEG][NCLS];
__device__ int   g_segoff[NSEG][NCLS];
__device__ float g_X[NCLS][FDIM][KPAD];
__device__ float g_cov[NCLS][FDIM][FDIM];
__device__ unsigned long long g_rotlog[NCLS][NSTEP][NPAIR];  // packed (c,s)
__device__ int   g_step[NCLS*FLAGSTRIDE];
__device__ float g_eval[NCLS][FDIM];
__device__ float g_W[NCLS][FDIM][FDIM];
__device__ float g_M[NCLS][DDIR][FDIM];
__device__ float g_mom[NCLS][DDIR][4];

union PackCS { float2 f; unsigned long long u; };
union PackF  { float f; unsigned int u; };

// round-robin tournament pairing: 255 fixed, 0..254 rotate
__device__ __forceinline__ void get_pair(int r, int s, int& p, int& q) {
    int a, b;
    if (s == 0) { a = NROUND; b = r; }
    else {
        a = r + s; if (a >= NROUND) a -= NROUND;
        b = r - s; if (b < 0) b += NROUND;
    }
    p = min(a, b); q = max(a, b);
}

__device__ __forceinline__ int tidx(int i, int j) { return ((i*(i+1))>>1) + j; } // i>=j
__device__ __forceinline__ int tidx2(int a, int b) { return a >= b ? tidx(a,b) : tidx(b,a); }

// ---- K0: zero compacted buffer + flags + segment counters ----
__global__ __launch_bounds__(1024) void k_zero() {
    int idx = blockIdx.x*blockDim.x + threadIdx.x;
    const int total = NCLS*FDIM*KPAD;
    float* x = &g_X[0][0][0];
    for (int i = idx; i < total; i += gridDim.x*blockDim.x) x[i] = 0.f;
    if (idx < NCLS*FLAGSTRIDE) g_step[idx] = 0;
    if (idx < NSEG*NCLS) (&g_segcnt[0][0])[idx] = 0;
}

// ---- K1: per-class sums per feature + counts; writes mu/ns directly ----
__global__ void k_sums(const float* __restrict__ feat, const int* __restrict__ lab) {
    __shared__ float acc[NCLS][256];
    __shared__ float cnt[NCLS][256];
    int t = threadIdx.x;
    int f = blockIdx.x;
    for (int c = 0; c < NCLS; ++c) { acc[c][t] = 0.f; cnt[c][t] = 0.f; }
    for (int j = 0; j < NPIX/256; ++j) {
        int n = t + 256*j;
        int b = n >> 12, hw = n & 4095;
        float v = feat[(size_t)b*1048576 + (size_t)f*4096 + hw];
        int c = lab[n];
        acc[c][t] += v;
        cnt[c][t] += 1.f;
    }
    __syncthreads();
    for (int off = 128; off > 0; off >>= 1) {
        if (t < off)
            for (int c = 0; c < NCLS; ++c) {
                acc[c][t] += acc[c][t+off];
                cnt[c][t] += cnt[c][t+off];
            }
        __syncthreads();
    }
    if (t < NCLS) {
        float ns = fmaxf(cnt[t][0], 1.f);
        g_mu[t][f] = acc[t][0] / ns;      // identical operands/order as old musetup
        if (f == 0) { g_cntf[t] = cnt[t][0]; g_ns[t] = ns; }
    }
}

// ---- K3a: deterministic per-segment rank + per-segment class counts ----
__global__ void k_rank(const int* __restrict__ lab) {
    __shared__ int sl[256];
    int seg = blockIdx.x, t = threadIdx.x;
    int n = seg*256 + t;
    int c = lab[n];
    sl[t] = c;
    __syncthreads();
    int rnk = 0, tot = 0;
    for (int i = 0; i < 256; ++i) {
        int e = sl[i];
        if (e == c) { tot += 1; if (i < t) rnk += 1; }
    }
    g_rank[n] = rnk;
    if (rnk == 0) g_segcnt[seg][c] = tot;
}

// ---- K3b: exclusive scan of segment counts per class ----
__global__ void k_segscan() {
    int c = threadIdx.x;
    if (c < NCLS) {
        int run = 0;
        for (int s = 0; s < NSEG; ++s) {
            g_segoff[s][c] = run;
            run += g_segcnt[s][c];
        }
    }
}

// ---- K4: scatter centered features into per-class compacted matrix ----
__global__ void k_scatter(const float* __restrict__ feat, const int* __restrict__ lab) {
    int n = blockIdx.x*256 + threadIdx.x;
    int g = blockIdx.y;
    int c = lab[n];
    int pos = g_segoff[n >> 8][c] + g_rank[n];
    float v = feat[(size_t)(n>>12)*1048576 + (size_t)g*4096 + (n&4095)] - g_mu[c][g];
    g_X[c][g][pos] = v;
}

// ---- K5: cov = (Xc Xc^T)/ns ----
__global__ void k_covgemm() {
    int cls = blockIdx.z, ti = blockIdx.y, tj = blockIdx.x;
    __shared__ float At[64][17], Bt[64][17];
    int t = threadIdx.x, tx = t & 15, ty = t >> 4;
    float accv[4][4] = {};
    for (int k0 = 0; k0 < KPAD; k0 += 16) {
        #pragma unroll
        for (int l = 0; l < 4; ++l) {
            int idx = t*4 + l;
            int row = idx >> 4, col = idx & 15;
            At[row][col] = g_X[cls][ti*64+row][k0+col];
            Bt[row][col] = g_X[cls][tj*64+row][k0+col];
        }
        __syncthreads();
        #pragma unroll
        for (int kk = 0; kk < 16; ++kk) {
            float a[4], b[4];
            #pragma unroll
            for (int i = 0; i < 4; ++i) a[i] = At[ty*4+i][kk];
            #pragma unroll
            for (int j = 0; j < 4; ++j) b[j] = Bt[tx*4+j][kk];
            #pragma unroll
            for (int i = 0; i < 4; ++i)
                #pragma unroll
                for (int j = 0; j < 4; ++j) accv[i][j] += a[i]*b[j];
        }
        __syncthreads();
    }
    float invns = 1.f / g_ns[cls];
    #pragma unroll
    for (int i = 0; i < 4; ++i)
        #pragma unroll
        for (int j = 0; j < 4; ++j)
            g_cov[cls][ti*64+ty*4+i][tj*64+tx*4+j] = accv[i][j]*invns;
}

// ---- K6: FUSED eigensolver (producer = Jacobi, consumer = V accumulation
//          + fused eigen-sort / W write) ----
__global__ __launch_bounds__(1024) void k_eigen() {
    extern __shared__ float smem[];
    int t = threadIdx.x;

    if (blockIdx.x < NCLS) {
        // ================= Jacobi producer =================
        float* pc  = smem;            // 128 cosines
        float* ps  = smem + 128;      // 128 sines
        float* tri = smem + 256;      // TRI_N floats
        int cls = blockIdx.x;

        for (int L = t; L < TRI_N; L += 1024) {
            int i = (int)((sqrtf(8.f*L+1.f)-1.f)*0.5f);
            while ((i+1)*(i+2)/2 <= L) ++i;
            while (i*(i+1)/2 > L) --i;
            int j = L - i*(i+1)/2;
            tri[L] = g_cov[cls][i][j];
        }
        // off-diagonal (s1<s2) register table: 8128 groups, <=8 per thread
        int my_s1[8], my_s2[8];
        int nmy = 0;
        #pragma unroll
        for (int k = 0; k < 8; ++k) {
            int gi = t + 1024*k;
            if (gi < NOFF) {
                int s2 = (int)((1.f + sqrtf(1.f + 8.f*gi))*0.5f);
                while (s2*(s2-1)/2 > gi) --s2;
                while ((s2+1)*s2/2 <= gi) ++s2;
                my_s1[nmy] = gi - s2*(s2-1)/2;
                my_s2[nmy] = s2;
                ++nmy;
            }
        }
        __syncthreads();

        for (int step = 0; step < NSTEP; ++step) {
            int r = step % NROUND;
            float cA = 1.f, sA = 0.f;
            if (t < NPAIR) {
                int p, q; get_pair(r, t, p, q);
                float app = tri[tidx(p,p)], aqq = tri[tidx(q,q)], apq = tri[tidx(q,p)];
                float c = 1.f, s = 0.f;
                if (fabsf(apq) > 1e-30f) {
                    float theta = (aqq - app) / (2.f*apq);
                    float tt = 1.f/(fabsf(theta) + sqrtf(theta*theta + 1.f));
                    if (theta < 0.f) tt = -tt;
                    c = 1.f/sqrtf(tt*tt + 1.f);
                    s = tt*c;
                }
                pc[t] = c; ps[t] = s;
                cA = c; sA = s;
                // diagonal 2x2 update (hazard-free: no off-diag group touches these)
                float napp = c*c*app - 2.f*c*s*apq + s*s*aqq;
                float naqq = s*s*app + 2.f*c*s*apq + c*c*aqq;
                tri[tidx(p,p)] = napp;
                tri[tidx(q,q)] = naqq;
                tri[tidx(q,p)] = 0.f;
            }
            __syncthreads();   // pc/ps + diag updates visible
            if (t < NPAIR) {
                PackCS pk; pk.f = make_float2(cA, sA);
                __hip_atomic_store(&g_rotlog[cls][step][t], pk.u,
                                   __ATOMIC_RELAXED, __HIP_MEMORY_SCOPE_AGENT);
            }

            for (int g = 0; g < nmy; ++g) {
                int s1 = my_s1[g], s2 = my_s2[g];
                float c1 = pc[s1], sv1 = ps[s1];
                float c2 = pc[s2], sv2 = ps[s2];
                int p1, q1; get_pair(r, s1, p1, q1);
                int p2, q2; get_pair(r, s2, p2, q2);
                float B00 = tri[tidx2(p1,p2)], B01 = tri[tidx2(p1,q2)];
                float B10 = tri[tidx2(q1,p2)], B11 = tri[tidx2(q1,q2)];
                float X00 = c1*B00 - sv1*B10, X01 = c1*B01 - sv1*B11;
                float X10 = sv1*B00 + c1*B10, X11 = sv1*B01 + c1*B11;
                tri[tidx2(p1,p2)] = c2*X00 - sv2*X01;
                tri[tidx2(p1,q2)] = sv2*X00 + c2*X01;
                tri[tidx2(q1,p2)] = c2*X10 - sv2*X11;
                tri[tidx2(q1,q2)] = sv2*X10 + c2*X11;
            }
            __syncthreads();   // drains rotlog store (vmcnt0) + all LDS
            if (t == 0) {
                __hip_atomic_store(&g_step[cls*FLAGSTRIDE], step+1,
                                   __ATOMIC_RELAXED, __HIP_MEMORY_SCOPE_AGENT);
            }
        }
        // publish eigenvalues (agent-scope -> LLC) then release final flag
        for (int f = t; f < FDIM; f += 1024) {
            PackF pf; pf.f = tri[tidx(f,f)];
            __hip_atomic_store((unsigned int*)&g_eval[cls][f], pf.u,
                               __ATOMIC_RELAXED, __HIP_MEMORY_SCOPE_AGENT);
        }
        __syncthreads();       // drains eval stores
        if (t == 0) {
            __hip_atomic_store(&g_step[cls*FLAGSTRIDE], NSTEP+1,
                               __ATOMIC_RELAXED, __HIP_MEMORY_SCOPE_AGENT);
        }
    } else {
        // ======= eigenvector consumer (+ fused sort / W write) =======
        float* lc = smem;
        float* ls = smem + 128;
        float* st = smem + 256;                 // 256 x VST state (64 V-columns)
        float* evbuf = smem + 256 + 256*VST;    // 256 eigenvalues (reuse tail)
        int*   rkbuf = (int*)(evbuf + 256);     // 256 ranks
        int rb = blockIdx.x - NCLS;
        int cls = rb >> 2;
        int ibase = (rb & 3) * 64;

        for (int idx = t; idx < 256*64; idx += 1024) {
            int p = idx >> 6, col = idx & 63;
            st[p*VST + col] = (p == ibase + col) ? 1.f : 0.f;
        }
        __syncthreads();

        int s0 = t >> 5;
        int cp = t & 31;
        for (int step = 0; step < NSTEP; ++step) {
            int r = step % NROUND;
            if (t == 0) {
                while (__hip_atomic_load(&g_step[cls*FLAGSTRIDE], __ATOMIC_RELAXED,
                                         __HIP_MEMORY_SCOPE_AGENT) <= step)
                    __builtin_amdgcn_s_sleep(2);
            }
            __syncthreads();
            if (t < NPAIR) {
                PackCS pk;
                pk.u = __hip_atomic_load(&g_rotlog[cls][step][t],
                                         __ATOMIC_RELAXED, __HIP_MEMORY_SCOPE_AGENT);
                lc[t] = pk.f.x; ls[t] = pk.f.y;
            }
            __syncthreads();
            float2 xv[4], yv[4];
            float cv[4], sv[4];
            int pa[4], qa[4];
            #pragma unroll
            for (int w = 0; w < 4; ++w) {
                int s = s0 + 32*w;
                cv[w] = lc[s]; sv[w] = ls[s];
                get_pair(r, s, pa[w], qa[w]);
                xv[w] = *(float2*)&st[pa[w]*VST + 2*cp];
                yv[w] = *(float2*)&st[qa[w]*VST + 2*cp];
            }
            #pragma unroll
            for (int w = 0; w < 4; ++w) {
                float2 nx, ny;
                nx.x = cv[w]*xv[w].x - sv[w]*yv[w].x;
                nx.y = cv[w]*xv[w].y - sv[w]*yv[w].y;
                ny.x = sv[w]*xv[w].x + cv[w]*yv[w].x;
                ny.y = sv[w]*xv[w].y + cv[w]*yv[w].y;
                *(float2*)&st[pa[w]*VST + 2*cp] = nx;
                *(float2*)&st[qa[w]*VST + 2*cp] = ny;
            }
        }
        // wait for eigenvalues, rank them (identical comparator to old k_sort)
        if (t == 0) {
            while (__hip_atomic_load(&g_step[cls*FLAGSTRIDE], __ATOMIC_RELAXED,
                                     __HIP_MEMORY_SCOPE_AGENT) <= NSTEP)
                __builtin_amdgcn_s_sleep(2);
        }
        __syncthreads();
        if (t < 256) {
            PackF pf;
            pf.u = __hip_atomic_load((unsigned int*)&g_eval[cls][t],
                                     __ATOMIC_RELAXED, __HIP_MEMORY_SCOPE_AGENT);
            evbuf[t] = pf.f;
        }
        __syncthreads();
        if (t < 256) {
            float mine = evbuf[t];
            int r = 0;
            for (int f = 0; f < 256; ++f) {
                float o = evbuf[f];
                if (o > mine || (o == mine && f < t)) ++r;
            }
            rkbuf[t] = r;
        }
        __syncthreads();
        for (int idx = t; idx < 256*32; idx += 1024) {
            int f = idx >> 5, c2 = idx & 31;
            float2 v = *(float2*)&st[f*VST + 2*c2];
            *(float2*)&g_W[cls][rkbuf[f]][ibase + 2*c2] = v;
        }
    }
}

// ---- K10: M[c] = proj @ W[c]   (D x F) ----
__global__ void k_mgemm(const float* __restrict__ pm) {
    int cls = blockIdx.z, dt = blockIdx.y, gt = blockIdx.x;
    __shared__ float At[64][17], Bt[16][65];
    int t = threadIdx.x, tx = t & 15, ty = t >> 4;
    float accv[4][4] = {};
    for (int k0 = 0; k0 < FDIM; k0 += 16) {
        #pragma unroll
        for (int l = 0; l < 4; ++l) {
            int idx = t*4 + l;
            int row = idx >> 4, col = idx & 15;
            At[row][col] = pm[(size_t)(dt*64+row)*FDIM + k0 + col];
        }
        #pragma unroll
        for (int l = 0; l < 4; ++l) {
            int idx = t*4 + l;
            int row = idx >> 6, col = idx & 63;
            Bt[row][col] = g_W[cls][k0+row][gt*64+col];
        }
        __syncthreads();
        #pragma unroll
        for (int kk = 0; kk < 16; ++kk) {
            float a[4], b[4];
            #pragma unroll
            for (int i = 0; i < 4; ++i) a[i] = At[ty*4+i][kk];
            #pragma unroll
            for (int j = 0; j < 4; ++j) b[j] = Bt[kk][tx*4+j];
            #pragma unroll
            for (int i = 0; i < 4; ++i)
                #pragma unroll
                for (int j = 0; j < 4; ++j) accv[i][j] += a[i]*b[j];
        }
        __syncthreads();
    }
    #pragma unroll
    for (int i = 0; i < 4; ++i)
        #pragma unroll
        for (int j = 0; j < 4; ++j)
            g_M[cls][dt*64+ty*4+i][gt*64+tx*4+j] = accv[i][j];
}

// ---- K11: fv = M[c] @ Xc, accumulate moments m1..m4 over columns ----
__global__ void k_fvmom() {
    int cls = blockIdx.y, dt = blockIdx.x;
    __shared__ float Mt[64][17], Xt[16][65];
    __shared__ float red[64][16];
    int t = threadIdx.x, tx = t & 15, ty = t >> 4;
    float mm[4][4] = {};
    for (int kt = 0; kt < KPAD; kt += 64) {
        float accv[4][4] = {};
        for (int g0 = 0; g0 < FDIM; g0 += 16) {
            #pragma unroll
            for (int l = 0; l < 4; ++l) {
                int idx = t*4 + l;
                int row = idx >> 4, col = idx & 15;
                Mt[row][col] = g_M[cls][dt*64+row][g0+col];
            }
            #pragma unroll
            for (int l = 0; l < 4; ++l) {
                int idx = t*4 + l;
                int row = idx >> 6, col = idx & 63;
                Xt[row][col] = g_X[cls][g0+row][kt+col];
            }
            __syncthreads();
            #pragma unroll
            for (int kk = 0; kk < 16; ++kk) {
                float a[4], b[4];
                #pragma unroll
                for (int i = 0; i < 4; ++i) a[i] = Mt[ty*4+i][kk];
                #pragma unroll
                for (int j = 0; j < 4; ++j) b[j] = Xt[kk][tx*4+j];
                #pragma unroll
                for (int i = 0; i < 4; ++i)
                    #pragma unroll
                    for (int j = 0; j < 4; ++j) accv[i][j] += a[i]*b[j];
            }
            __syncthreads();
        }
        #pragma unroll
        for (int i = 0; i < 4; ++i)
            #pragma unroll
            for (int j = 0; j < 4; ++j) {
                float v = accv[i][j], v2 = v*v;
                mm[0][i] += v; mm[1][i] += v2; mm[2][i] += v2*v; mm[3][i] += v2*v2;
            }
    }
    #pragma unroll
    for (int m = 0; m < 4; ++m) {
        __syncthreads();
        #pragma unroll
        for (int i = 0; i < 4; ++i) red[ty*4+i][tx] = mm[m][i];
        __syncthreads();
        if (t < 64) {
            float s = 0.f;
            #pragma unroll
            for (int x = 0; x < 16; ++x) s += red[t][x];
            g_mom[cls][dt*64 + t][m] = s;
        }
    }
}

// ---- K12: kurtosis, clip, weighted mean -> loss ----
__global__ __launch_bounds__(1024) void k_loss(float* __restrict__ out) {
    __shared__ float red[1024];
    int t = threadIdx.x;
    float sum = 0.f;
    for (int id = t; id < NCLS*DDIR; id += 1024) {
        int c = id >> 10, d = id & 1023;
        float cntv = g_cntf[c];
        if (cntv > 0.f) {
            float invns = 1.f / g_ns[c];
            float m1 = g_mom[c][d][0]*invns;
            float m2 = g_mom[c][d][1]*invns;
            float m3 = g_mom[c][d][2]*invns;
            float m4 = g_mom[c][d][3]*invns;
            float var = fmaxf(m2 - m1*m1, 1e-16f);
            float m4c = -3.f*m1*m1*m1*m1 + 6.f*m2*m1*m1 - 4.f*m3*m1 + m4;
            float kurt = m4c/(var*var) - 3.f;
            kurt = fminf(fmaxf(kurt, -3.f), 3.f);
            sum += kurt*kurt;
        }
    }
    red[t] = sum;
    __syncthreads();
    for (int off = 512; off > 0; off >>= 1) {
        if (t < off) red[t] += red[t+off];
        __syncthreads();
    }
    if (t == 0) {
        float na = 0.f;
        for (int c = 0; c < NCLS; ++c) na += (g_cntf[c] > 0.f) ? 1.f : 0.f;
        na = fmaxf(na, 1.f);
        out[0] = red[0] / ((float)DDIR * na);
    }
}

extern "C" void kernel_launch(void* const* d_in, const int* in_sizes, int n_in,
                              void* d_out, int out_size, void* d_ws, size_t ws_size,
                              hipStream_t stream) {
    const float* feat = (const float*)d_in[0];
    const int*   lab  = (const int*)d_in[1];
    const float* pm   = (const float*)d_in[2];
    float* out = (float*)d_out;

    const int eig_lds = (256 + TRI_N) * 4 + 64;   // producer needs the max

    (void)hipFuncSetAttribute((const void*)k_eigen,
        hipFuncAttributeMaxDynamicSharedMemorySize, eig_lds);

    hipLaunchKernelGGL(k_zero, dim3(3648), dim3(1024), 0, stream);
    hipLaunchKernelGGL(k_sums, dim3(256), dim3(256), 0, stream, feat, lab);
    hipLaunchKernelGGL(k_rank, dim3(NSEG), dim3(256), 0, stream, lab);
    hipLaunchKernelGGL(k_segscan, dim3(1), dim3(64), 0, stream);
    hipLaunchKernelGGL(k_scatter, dim3(32, 256), dim3(256), 0, stream, feat, lab);
    hipLaunchKernelGGL(k_covgemm, dim3(4, 4, NCLS), dim3(256), 0, stream);
    hipLaunchKernelGGL(k_eigen, dim3(NCLS + NCLS*4), dim3(1024), eig_lds, stream);
    hipLaunchKernelGGL(k_mgemm, dim3(4, 16, NCLS), dim3(256), 0, stream, pm);
    hipLaunchKernelGGL(k_fvmom, dim3(16, NCLS), dim3(256), 0, stream);
    hipLaunchKernelGGL(k_loss, dim3(1), dim3(1024), 0, stream, out);
}